// Round 2
// baseline (834.473 us; speedup 1.0000x reference)
//
#include <hip/hip_runtime.h>
#include <stdint.h>

// Problem constants
constexpr int BB = 64;     // batch
constexpr int SS = 512;    // seq len
constexpr int DD = 256;    // emb dim
constexpr int HH = 256;    // hidden
constexpr int NHH = 4;     // heads
constexpr int KK = 1024;   // NH*H recurrent input dim

// HARD FACTS (r2-r9): VGPR budget = 128 iff static LDS forces <=2 WG/CU,
// else 64; never more (launch_bounds/waves_per_eu/AGPR all failed). Step
// time == streamed_weight_bytes / 64 B/cyc (r7). Relaxed self-tagged
// exchange ~0.3-0.5us/step; release/acquire ~4us/step (r6). fp8/int8
// weights break accuracy (r8).
//
// ROUND 12: R11 post-mortem -- predicted VGPR>=100, measured 56: the
// "+v"-pinned weight slab is STILL not register-resident (compiler refuses
// big regfiles for this kernel; consistent with r2-r9). Step time 1.12us =
// 853ns weight stream (r7 law, 128KB @ 64B/cyc from L2) + ~270ns chain.
// The R11 gain was the schedule trim only. Therefore: stop fighting the
// register allocator -- put the 128KB slab in LDS (160KB/CU available,
// >=128KB/WG supported on gfx950). 1 WG/CU, 256 WGs on 256 CUs.
//  - Wq global layout pre-swizzled (slot = m ^ (t&15)) so staging is a
//    verbatim linear copy (conflict-free ds_write) and matvec ds_read_b128
//    at stride 256B hits the 8-cyc/wave floor instead of 32-way conflict.
//  - c-operand (ap) read keeps wave-uniform broadcast (logical-m order).
//  - schedule, exchange protocol, epilogue identical to R11 (race audit
//    unchanged: publish c(k) slot k&1 tag k+1; overwrite of slot k&1 by
//    c(k+2) is post-B2(k+1) which transitively requires peers consumed
//    c(k)).
constexpr int TT = 512;
constexpr int RECUR_LDS = 134656;  // 128K weights + 512 cbuf + 2K partials + 1K hbuf

typedef _Float16 f16;
typedef _Float16 f16x2 __attribute__((ext_vector_type(2)));

__device__ inline float dot2p(uint32_t a, uint32_t b, float c) {
  f16x2 av = __builtin_bit_cast(f16x2, a);
  f16x2 bv = __builtin_bit_cast(f16x2, b);
#if defined(__has_builtin)
#if __has_builtin(__builtin_amdgcn_fdot2)
  return __builtin_amdgcn_fdot2(av, bv, c, false);
#else
  return c + (float)av.x * (float)bv.x + (float)av.y * (float)bv.y;
#endif
#else
  return c + (float)av.x * (float)bv.x + (float)av.y * (float)bv.y;
#endif
}

__device__ inline float dot8(uint4 w, uint4 a, float c) {
  c = dot2p(w.x, a.x, c);
  c = dot2p(w.y, a.y, c);
  c = dot2p(w.z, a.z, c);
  c = dot2p(w.w, a.w, c);
  return c;
}

__device__ inline uint32_t pack2(float a, float b) {
  f16x2 v;
  v.x = (f16)a;
  v.y = (f16)b;
  return __builtin_bit_cast(uint32_t, v);
}

__device__ inline float fast_tanh(float x) {
  x = fminf(fmaxf(x, -15.f), 15.f);
  float e = __expf(2.f * x);
  return 1.f - 2.f / (e + 1.f);
}

// ---------------------------------------------------------------------------
// Prep A1: pack Wh [256,1024] fp32 -> Wq f16, PRE-SWIZZLED for LDS:
// Wq[p*8192 + t*16 + j] where j = physical slot, logical m = j ^ (t&15).
// Holds Wh[64p + o_loc][256n + 128*ch2 + 8m .. +8) as 8 packed f16
// (out=t&255, n=out>>6, o_loc=out&63, ch2=t>>8).
// ---------------------------------------------------------------------------
__global__ void k_pack_wq(const float* __restrict__ Wh, uint4* __restrict__ Wq) {
  int gid = blockIdx.x * blockDim.x + threadIdx.x;  // 32768
  int p = gid >> 13;
  int t = (gid >> 4) & 511;
  int j = gid & 15;        // physical slot
  int m = j ^ (t & 15);    // logical m stored at this slot
  int out = t & 255, ch2 = t >> 8;
  int n = out >> 6, o_loc = out & 63;
  const float* s = Wh + (64 * p + o_loc) * KK + 256 * n + 128 * ch2 + 8 * m;
  uint4 w;
  w.x = pack2(s[0], s[1]);
  w.y = pack2(s[2], s[3]);
  w.z = pack2(s[4], s[5]);
  w.w = pack2(s[6], s[7]);
  Wq[gid] = w;  // gid = p*8192 + t*16 + j -> coalesced 16B stores
}

// ---------------------------------------------------------------------------
// Prep A2/A3: transpose src[r, C] (r in [0,256)) -> dst[c*256 + r]
// ---------------------------------------------------------------------------
__global__ void k_transpose8(const float* __restrict__ src, float* __restrict__ dst,
                             int C, int total) {
  int gid = blockIdx.x * blockDim.x + threadIdx.x;
  if (gid >= total) return;
  int r = gid & 255, c = gid >> 8;
  dst[gid] = src[r * C + c];
}

// ---------------------------------------------------------------------------
// Prep B: U[row, o] = emb[src[row]] @ Wi^T + bi + bh (f16). Blocks beyond
// input_len[b] skipped.
// ---------------------------------------------------------------------------
__global__ __launch_bounds__(256) void k_precompute_u(
    const int* __restrict__ src, const float* __restrict__ emb,
    const float* __restrict__ WiT, const float* __restrict__ bi,
    const float* __restrict__ bh, const int* __restrict__ input_len,
    f16* __restrict__ U) {
  const int row0 = blockIdx.x * 32;
  const int b = row0 >> 9;
  if ((row0 & 511) >= input_len[b]) return;
  __shared__ float xs[32 * 256];
  __shared__ int srcs[32];
  const int tid = threadIdx.x;
  if (tid < 32) srcs[tid] = src[row0 + tid];
  __syncthreads();
  for (int i = tid; i < 32 * 256; i += 256) {
    int r = i >> 8, d = i & 255;
    xs[i] = emb[srcs[r] * DD + d];
  }
  __syncthreads();
  const int o = tid;
  float acc[32];
#pragma unroll
  for (int r = 0; r < 32; ++r) acc[r] = 0.f;
  for (int d0 = 0; d0 < 256; d0 += 8) {
    float w[8];
#pragma unroll
    for (int j = 0; j < 8; ++j) w[j] = WiT[(d0 + j) * 256 + o];  // coalesced
#pragma unroll
    for (int r = 0; r < 32; ++r) {
      const float4* xp = (const float4*)(xs + r * 256 + d0);  // broadcast
      float4 x0 = xp[0], x1 = xp[1];
      acc[r] += x0.x * w[0] + x0.y * w[1] + x0.z * w[2] + x0.w * w[3] +
                x1.x * w[4] + x1.y * w[5] + x1.z * w[6] + x1.w * w[7];
    }
  }
  float bias = bi[o] + bh[o];
#pragma unroll
  for (int r = 0; r < 32; ++r)
    U[(size_t)(row0 + r) * HH + o] = (f16)(acc[r] + bias);
}

// ---------------------------------------------------------------------------
// Main recurrence (v-form): 4 WGs (512 thr) per batch, blockIdx = p*64 + b
// (same-XCD heuristic; correctness is placement-independent). Thread t:
// out = t&255 (n=out>>6, o_loc=out&63), ch2 = t>>8 (input half).
// Weights: 128 KB slab in LDS (staged once, verbatim copy of pre-swizzled
// Wq). 134.7 KB LDS total -> 1 WG/CU; 256 WGs on 256 CUs (co-resident).
// Per-step schedule (2 barriers):
//   [poll window] wave0: prefetch U(s+1), 4 gates | waves1-3: gather c(s)
//   B1 | all: matvec (LDS weights) -> partials; t<256: h-update | B2
//   wave0: v-update (regs) -> z -> c(s+1) -> publish + cbuf write
// ---------------------------------------------------------------------------
__global__ void __attribute__((amdgpu_flat_work_group_size(512, 512)))
k_recurrence(
    const uint4* __restrict__ Wq, const f16* __restrict__ U,
    const float* __restrict__ fix_src, const int* __restrict__ input_len,
    const float* __restrict__ fc1T, const float* __restrict__ fc1_b,
    const float* __restrict__ fc2_W, const float* __restrict__ fc2_b,
    float* __restrict__ out, uint32_t* __restrict__ Cex,
    float* __restrict__ FPg, int* __restrict__ Flg) {
  extern __shared__ __align__(16) char arena[];
  uint4* wl = (uint4*)arena;                     // [0,131072): weight slab
  f16* cbuf = (f16*)(arena + 131072);            // [131072,131584): c f16[256]
  uint4* cvec = (uint4*)(arena + 131072);        // same bytes, 32 uint4
  float* partials = (float*)(arena + 131584);    // 512 floats
  float* hbuf = (float*)(arena + 133632);        // 256 floats

  const int idx = blockIdx.x;
  const int b = idx & 63;
  const int p = idx >> 6;
  const int t = threadIdx.x;
  const int out_i = t & 255, ch2 = t >> 8;
  const int n = out_i >> 6, o_loc = out_i & 63;

  // one-time: stage this CU's 128 KB pre-swizzled slab into LDS.
  // Thread t copies uint4 indices {t, t+512, ...}: coalesced global reads,
  // lane-contiguous ds_writes. Visibility to other threads via B1 of iter 0.
  {
    const uint4* wsrc = Wq + p * 8192;
#pragma unroll
    for (int k2 = 0; k2 < 16; ++k2) wl[t + 512 * k2] = wsrc[t + 512 * k2];
  }

  // wave0 register state: v_n[64p + lane] for n=0..3
  float v0 = 0.f, v1 = 0.f, v2 = 0.f, v3 = 0.f;
  float h = 0.f;  // h_n[64p + o_loc] on threads t<256

  const int len = input_len[b];
  const f16* Ub = U + (size_t)b * SS * HH;
  const float* fsb = fix_src + b * SS;

  // prologue: c(0) = tanh(U(0)), publish slot 0 / tag 1. Own-region cbuf
  // write is ordered before the first matvec by B1 of iteration 0.
  if (t < 64) {
    float c0 = fast_tanh((float)Ub[64 * p + t]);
    f16 chv = (f16)c0;
    cbuf[64 * p + t] = chv;
    uint32_t dwp =
        ((uint32_t)__builtin_bit_cast(unsigned short, chv) << 16) | 1u;
    __hip_atomic_store(&Cex[b * 256 + p * 64 + t], dwp, __ATOMIC_RELAXED,
                       __HIP_MEMORY_SCOPE_AGENT);
  }

  const int tsw = t & 15;
  const uint4* wrow = wl + t * 16;

#pragma unroll 1
  for (int s = 0; s < len; ++s) {
    const int par = s & 1;
    const uint32_t tag = (uint32_t)((s + 1) & 0xffff);
    const float dval = fsb[s];
    float g = 0.f, gq1 = 0.f, gq2 = 0.f, gq3 = 0.f, ufn = 0.f;

    if (t < 64) {
      // prefetch U(s+1) (clamped: rows >= len are poison) + 4 gates,
      // all during the peers' poll window -> off the serial chain
      int sn = (s + 1 < len) ? (s + 1) : s;
      ufn = (float)Ub[(size_t)sn * HH + 64 * p + t];
      g   = 1.f / (1.f + __expf(0.f - dval));  // n=0 (own h-gate too)
      gq1 = 1.f / (1.f + __expf(3.f - dval));
      gq2 = 1.f / (1.f + __expf(6.f - dval));
      gq3 = 1.f / (1.f + __expf(9.f - dval));
    } else if (t < 256) {
      g = 1.f / (1.f + __expf((float)(3 * n) - dval));
      // waves 1..3: each gathers one peer's 64 self-tagged dwords
      int wv = t >> 6;       // 1,2,3
      int lane = t & 63;
      int q = (p + wv) & 3;  // peer CU
      uint32_t* addr = &Cex[((par * 64 + b) * 4 + q) * 64 + lane];
      uint32_t dw;
      do {
        dw = __hip_atomic_load(addr, __ATOMIC_RELAXED,
                               __HIP_MEMORY_SCOPE_AGENT);
      } while ((dw & 0xffffu) != tag);
      cbuf[64 * q + lane] =
          __builtin_bit_cast(f16, (unsigned short)(dw >> 16));
    }
    __syncthreads();  // B1: full c(s) in cbuf (+ staging visible, iter 0)

    // matvec: thread covers (n, o_loc) x 128 inputs; weights from LDS.
    // wrow[m ^ tsw] = swizzled slot -> 8-access/bank floor, no 32-way
    // conflict; ap[m] wave-uniform broadcast.
    float acc = 0.f;
    const uint4* ap = cvec + ch2 * 16;
#pragma unroll
    for (int m = 0; m < 16; ++m) acc = dot8(wrow[m ^ tsw], ap[m], acc);
    partials[t] = acc;  // t = ch2*256 + out_i

    // h-update off the serial chain (reads own-region c(s); own region is
    // only overwritten post-B2)
    if (t < 256) {
      float cown = (float)cbuf[64 * p + o_loc];
      h = g * cown + (1.f - g) * h;
    }
    __syncthreads();  // B2: partials complete

    if (t < 64) {
      float w0 = partials[t]       + partials[256 + t];
      float w1 = partials[64 + t]  + partials[320 + t];
      float w2 = partials[128 + t] + partials[384 + t];
      float w3 = partials[192 + t] + partials[448 + t];
      v0 = g   * w0 + (1.f - g)   * v0;
      v1 = gq1 * w1 + (1.f - gq1) * v1;
      v2 = gq2 * w2 + (1.f - gq2) * v2;
      v3 = gq3 * w3 + (1.f - gq3) * v3;
      float c = fast_tanh(ufn + (v0 + v1 + v2 + v3));
      f16 chv = (f16)c;
      uint32_t dwp =
          ((uint32_t)__builtin_bit_cast(unsigned short, chv) << 16) |
          (uint32_t)((s + 2) & 0xffff);
      __hip_atomic_store(
          &Cex[(((s + 1) & 1) * 64 + b) * 256 + p * 64 + t], dwp,
          __ATOMIC_RELAXED, __HIP_MEMORY_SCOPE_AGENT);
      cbuf[64 * p + t] = chv;  // next-iter matvec reads after B1
    }
    // no B3: peer-region cbuf rewrites (next iter, pre-B1) only race with
    // reads that completed before B2; own-region rewrite is post-B2.
  }

  // ---- epilogue: fc1 partial over this CU's 256 k's, then one-time sync
  if (t < 256) hbuf[out_i] = h;  // hbuf[k_loc]: n=k_loc>>6, i=64p+(k_loc&63)
  __syncthreads();
  {
    float acc = 0.f;
#pragma unroll 4
    for (int r = 0; r < 128; ++r) {
      int k_loc = ch2 * 128 + r;
      int n2 = k_loc >> 6, il = k_loc & 63;
      int kg = n2 * 256 + 64 * p + il;
      acc += hbuf[k_loc] * fc1T[(size_t)kg * 256 + out_i];
    }
    partials[t] = acc;
  }
  __syncthreads();
  if (t < 256) FPg[(b * 4 + p) * 256 + out_i] =
      partials[out_i] + partials[256 + out_i];
  __syncthreads();  // barrier drains stores before flag
  if (t == 0)
    __hip_atomic_store(&Flg[b * 4 + p], 0x5A5A5A5A, __ATOMIC_RELEASE,
                       __HIP_MEMORY_SCOPE_AGENT);
  if (p != 0) return;
  if (t < 4 && t > 0) {
    while (__hip_atomic_load(&Flg[b * 4 + t], __ATOMIC_ACQUIRE,
                             __HIP_MEMORY_SCOPE_AGENT) != 0x5A5A5A5A) {
    }
  }
  __syncthreads();
  if (t < 256) {
    float pre = fc1_b[t];
#pragma unroll
    for (int q = 0; q < 4; ++q)
      pre += __hip_atomic_load(&FPg[(b * 4 + q) * 256 + t], __ATOMIC_RELAXED,
                               __HIP_MEMORY_SCOPE_AGENT);
    hbuf[t] = fast_tanh(pre);  // reuse as hid
  }
  __syncthreads();
  if (t < 64) {
    float p0 = 0.f, p1 = 0.f;
    for (int oi = t; oi < 256; oi += 64) {
      float hh = hbuf[oi];
      p0 += hh * fc2_W[oi];
      p1 += hh * fc2_W[256 + oi];
    }
#pragma unroll
    for (int off = 32; off; off >>= 1) {
      p0 += __shfl_down(p0, off);
      p1 += __shfl_down(p1, off);
    }
    if (t == 0) {
      out[b * 2 + 0] = p0 + fc2_b[0];
      out[b * 2 + 1] = p1 + fc2_b[1];
    }
  }
}

// ---------------------------------------------------------------------------
// Host launcher
// ws: [0,512K) Wq | [512K,768K) WiT | [768K,1792K) fc1T | [1792K,18176K) U
//     | [18176K,18304K) Cex | [18304K,18560K) FPg | [18560K,+1K) Flg
// Cex/Flg need no init: 0xAA poison never matches a tag (0xAAAA>512) or the
// 0x5A5A5A5A magic.
// ---------------------------------------------------------------------------
extern "C" void kernel_launch(void* const* d_in, const int* in_sizes, int n_in,
                              void* d_out, int out_size, void* d_ws, size_t ws_size,
                              hipStream_t stream) {
  const int* src = (const int*)d_in[0];
  const int* input_len = (const int*)d_in[1];
  const float* fix_src = (const float*)d_in[2];
  const float* emb = (const float*)d_in[3];
  const float* Wi = (const float*)d_in[4];
  const float* bi = (const float*)d_in[5];
  const float* Wh = (const float*)d_in[6];
  const float* bh = (const float*)d_in[7];
  const float* fc1_W = (const float*)d_in[8];
  const float* fc1_b = (const float*)d_in[9];
  const float* fc2_W = (const float*)d_in[10];
  const float* fc2_b = (const float*)d_in[11];
  float* out = (float*)d_out;

  char* ws = (char*)d_ws;
  uint4* Wq = (uint4*)(ws);                          // 512 KB
  float* WiT = (float*)(ws + (512ull << 10));        // 256 KB
  float* fc1T = (float*)(ws + (768ull << 10));       // 1 MB
  f16* U = (f16*)(ws + (1792ull << 10));             // 16 MB
  uint32_t* Cex = (uint32_t*)(ws + (18176ull << 10)); // 128 KB
  float* FPg = (float*)(ws + (18304ull << 10));      // 256 KB
  int* Flg = (int*)(ws + (18560ull << 10));          // 1 KB
  const size_t needed = (18561ull << 10);
  if (ws_size < needed) return;

  // one-time: allow >64 KB dynamic LDS for k_recurrence (host-side, not a
  // stream op -- safe under graph capture)
  static bool attr_set = false;
  if (!attr_set) {
    hipFuncSetAttribute((const void*)k_recurrence,
                        hipFuncAttributeMaxDynamicSharedMemorySize, RECUR_LDS);
    attr_set = true;
  }

  k_pack_wq<<<128, 256, 0, stream>>>(Wh, Wq);
  k_transpose8<<<(65536 + 255) / 256, 256, 0, stream>>>(Wi, WiT, 256, 65536);
  k_transpose8<<<(262144 + 255) / 256, 256, 0, stream>>>(fc1_W, fc1T, 1024, 262144);
  k_precompute_u<<<BB * SS / 32, 256, 0, stream>>>(src, emb, WiT, bi, bh,
                                                   input_len, U);
  k_recurrence<<<BB * 4, TT, RECUR_LDS, stream>>>(Wq, U, fix_src, input_len,
                                                  fc1T, fc1_b, fc2_W, fc2_b,
                                                  out, Cex, FPg, Flg);
}

// Round 4
// 789.428 us; speedup vs baseline: 1.0571x; 1.0571x over previous
//
#include <hip/hip_runtime.h>
#include <stdint.h>

// Problem constants
constexpr int BB = 64;     // batch
constexpr int SS = 512;    // seq len
constexpr int DD = 256;    // emb dim
constexpr int HH = 256;    // hidden
constexpr int NHH = 4;     // heads
constexpr int KK = 1024;   // NH*H recurrent input dim

// HARD FACTS (r2-r9, updated R12): VGPR budget = 128 in the 2-WG/CU class;
// BUT >80KB dynamic LDS forces 1 WG/CU = 2 waves/SIMD = 256-VGPR budget
// (new regime, untested by r2-r9). Step time == streamed_weight_bytes /
// 64 B/cyc when weights come from L2 (r7; R11 measured 2048+640 cyc
// exactly). LDS pipe: all-LDS weights = 2176 cyc/step through one pipe
// (R12 measured, REGRESSION vs split pipes). Relaxed self-tagged exchange
// chain = 640 cyc/step (R11). fp8/int8 weights break accuracy (r8).
//
// ROUND 14 == R13 with the compile fix: the uint4 "+v" tie is not
// supported ("tied indirect register inputs"); pin per 32-bit component
// instead (the exact form that compiled in R10/R11). Register residency
// via OPAQUE asm global_load_dwordx4 ("=v" pure-output constraint on
// uint4 compiles fine): the compiler cannot rematerialize asm results;
// with 1 WG/CU (84KB LDS pad) budget=256, demand ~110 -> no spill
// pressure. Weight traffic per step: ZERO. Step = chain(640) + ap uniform
// reads(640) + dot(256) + tail(~200) ~= 725 ns.
// Schedule/exchange/epilogue = R11 (2 barriers, fence-free self-tagged
// parity exchange; race audit unchanged).
constexpr int TT = 512;
constexpr int RECUR_LDS = 86016;  // 84 KB pad -> 1 WG/CU (>(160/2) KB)

typedef _Float16 f16;
typedef _Float16 f16x2 __attribute__((ext_vector_type(2)));

__device__ inline float dot2p(uint32_t a, uint32_t b, float c) {
  f16x2 av = __builtin_bit_cast(f16x2, a);
  f16x2 bv = __builtin_bit_cast(f16x2, b);
#if defined(__has_builtin)
#if __has_builtin(__builtin_amdgcn_fdot2)
  return __builtin_amdgcn_fdot2(av, bv, c, false);
#else
  return c + (float)av.x * (float)bv.x + (float)av.y * (float)bv.y;
#endif
#else
  return c + (float)av.x * (float)bv.x + (float)av.y * (float)bv.y;
#endif
}

__device__ inline float dot8(uint4 w, uint4 a, float c) {
  c = dot2p(w.x, a.x, c);
  c = dot2p(w.y, a.y, c);
  c = dot2p(w.z, a.z, c);
  c = dot2p(w.w, a.w, c);
  return c;
}

__device__ inline uint32_t pack2(float a, float b) {
  f16x2 v;
  v.x = (f16)a;
  v.y = (f16)b;
  return __builtin_bit_cast(uint32_t, v);
}

__device__ inline float fast_tanh(float x) {
  x = fminf(fmaxf(x, -15.f), 15.f);
  float e = __expf(2.f * x);
  return 1.f - 2.f / (e + 1.f);
}

// ---------------------------------------------------------------------------
// Prep A1: pack Wh [256,1024] fp32 -> Wq f16 for the v-form matvec.
// Wq[(p*16 + m)*512 + t] (slot-major): t -> out=t&255 (n=out>>6,
// o_loc=out&63), ch2=t>>8. Holds Wh[64p + o_loc][256n + 128*ch2 + 8m .. +8)
// as 8 packed f16. Slot-major => one-time register load is perfectly
// coalesced (lane-contiguous uint4 per slot).
// ---------------------------------------------------------------------------
__global__ void k_pack_wq(const float* __restrict__ Wh, uint4* __restrict__ Wq) {
  int gid = blockIdx.x * blockDim.x + threadIdx.x;  // 32768
  int p = gid >> 13;
  int m = (gid >> 9) & 15;
  int t = gid & 511;
  int out = t & 255, ch2 = t >> 8;
  int n = out >> 6, o_loc = out & 63;
  const float* s = Wh + (64 * p + o_loc) * KK + 256 * n + 128 * ch2 + 8 * m;
  uint4 w;
  w.x = pack2(s[0], s[1]);
  w.y = pack2(s[2], s[3]);
  w.z = pack2(s[4], s[5]);
  w.w = pack2(s[6], s[7]);
  Wq[gid] = w;
}

// ---------------------------------------------------------------------------
// Prep A2/A3: transpose src[r, C] (r in [0,256)) -> dst[c*256 + r]
// ---------------------------------------------------------------------------
__global__ void k_transpose8(const float* __restrict__ src, float* __restrict__ dst,
                             int C, int total) {
  int gid = blockIdx.x * blockDim.x + threadIdx.x;
  if (gid >= total) return;
  int r = gid & 255, c = gid >> 8;
  dst[gid] = src[r * C + c];
}

// ---------------------------------------------------------------------------
// Prep B: U[row, o] = emb[src[row]] @ Wi^T + bi + bh (f16). Blocks beyond
// input_len[b] skipped.
// ---------------------------------------------------------------------------
__global__ __launch_bounds__(256) void k_precompute_u(
    const int* __restrict__ src, const float* __restrict__ emb,
    const float* __restrict__ WiT, const float* __restrict__ bi,
    const float* __restrict__ bh, const int* __restrict__ input_len,
    f16* __restrict__ U) {
  const int row0 = blockIdx.x * 32;
  const int b = row0 >> 9;
  if ((row0 & 511) >= input_len[b]) return;
  __shared__ float xs[32 * 256];
  __shared__ int srcs[32];
  const int tid = threadIdx.x;
  if (tid < 32) srcs[tid] = src[row0 + tid];
  __syncthreads();
  for (int i = tid; i < 32 * 256; i += 256) {
    int r = i >> 8, d = i & 255;
    xs[i] = emb[srcs[r] * DD + d];
  }
  __syncthreads();
  const int o = tid;
  float acc[32];
#pragma unroll
  for (int r = 0; r < 32; ++r) acc[r] = 0.f;
  for (int d0 = 0; d0 < 256; d0 += 8) {
    float w[8];
#pragma unroll
    for (int j = 0; j < 8; ++j) w[j] = WiT[(d0 + j) * 256 + o];  // coalesced
#pragma unroll
    for (int r = 0; r < 32; ++r) {
      const float4* xp = (const float4*)(xs + r * 256 + d0);  // broadcast
      float4 x0 = xp[0], x1 = xp[1];
      acc[r] += x0.x * w[0] + x0.y * w[1] + x0.z * w[2] + x0.w * w[3] +
                x1.x * w[4] + x1.y * w[5] + x1.z * w[6] + x1.w * w[7];
    }
  }
  float bias = bi[o] + bh[o];
#pragma unroll
  for (int r = 0; r < 32; ++r)
    U[(size_t)(row0 + r) * HH + o] = (f16)(acc[r] + bias);
}

// ---------------------------------------------------------------------------
// Main recurrence (v-form): 4 WGs (512 thr) per batch, blockIdx = p*64 + b
// (same-XCD heuristic; correctness is placement-independent). Thread t:
// out = t&255 (n=out>>6, o_loc=out&63), ch2 = t>>8 (input half).
// Weights: 16 uint4/thread, loaded ONCE via opaque asm loads -> VGPRs for
// the whole kernel (84 KB LDS pad -> 1 WG/CU -> 256-VGPR budget, demand
// ~110). Per-step weight traffic: zero.
// Per-step schedule (2 barriers):
//   [poll window] wave0: prefetch U(s+1), 4 gates | waves1-3: gather c(s)
//   B1 | all: matvec (reg weights, LDS ap) -> partials; t<256: h-update
//   B2 | wave0: v-update (regs) -> z -> c(s+1) -> publish + cbuf write
// ---------------------------------------------------------------------------
__global__ void __attribute__((amdgpu_flat_work_group_size(512, 512),
                               amdgpu_waves_per_eu(2)))
k_recurrence(
    const uint4* __restrict__ Wq, const f16* __restrict__ U,
    const float* __restrict__ fix_src, const int* __restrict__ input_len,
    const float* __restrict__ fc1T, const float* __restrict__ fc1_b,
    const float* __restrict__ fc2_W, const float* __restrict__ fc2_b,
    float* __restrict__ out, uint32_t* __restrict__ Cex,
    float* __restrict__ FPg, int* __restrict__ Flg) {
  extern __shared__ __align__(16) char arena[];
  f16* cbuf = (f16*)arena;                    // [0,512): c as f16[256]
  uint4* cvec = (uint4*)arena;                // same bytes, 32 uint4
  float* partials = (float*)(arena + 512);    // [512,2560): 512 floats
  float* hbuf = (float*)(arena + 2560);       // [2560,3584): 256 floats

  const int idx = blockIdx.x;
  const int b = idx & 63;
  const int p = idx >> 6;
  const int t = threadIdx.x;
  const int out_i = t & 255, ch2 = t >> 8;
  const int n = out_i >> 6, o_loc = out_i & 63;

  // one-time: this CU's 128 KB weight slab -> 64 VGPRs via OPAQUE asm
  // loads. The compiler cannot rematerialize asm outputs; with 256-reg
  // budget and ~110 demand it has no reason to spill them either.
  uint4 w[16];
  {
    const uint4* wp = Wq + (p * 16) * TT + t;
#pragma unroll
    for (int m = 0; m < 16; ++m) {
      const uint4* a = wp + m * TT;
      asm volatile("global_load_dwordx4 %0, %1, off"
                   : "=v"(w[m]) : "v"(a) : "memory");
    }
    asm volatile("s_waitcnt vmcnt(0)" ::: "memory");
  }

  // wave0 register state: v_n[64p + lane] for n=0..3
  float v0 = 0.f, v1 = 0.f, v2 = 0.f, v3 = 0.f;
  float h = 0.f;  // h_n[64p + o_loc] on threads t<256

  const int len = input_len[b];
  const f16* Ub = U + (size_t)b * SS * HH;
  const float* fsb = fix_src + b * SS;

  // prologue: c(0) = tanh(U(0)), publish slot 0 / tag 1. Own-region cbuf
  // write is ordered before the first matvec by B1 of iteration 0.
  if (t < 64) {
    float c0 = fast_tanh((float)Ub[64 * p + t]);
    f16 chv = (f16)c0;
    cbuf[64 * p + t] = chv;
    uint32_t dwp =
        ((uint32_t)__builtin_bit_cast(unsigned short, chv) << 16) | 1u;
    __hip_atomic_store(&Cex[b * 256 + p * 64 + t], dwp, __ATOMIC_RELAXED,
                       __HIP_MEMORY_SCOPE_AGENT);
  }

#pragma unroll 1
  for (int s = 0; s < len; ++s) {
    // residency pin: w[] must be live-in to every iteration in VGPRs.
    // NOTE: per-32-bit-component ties only -- uint4 "+v" does not compile
    // ("tied indirect register inputs").
#pragma unroll
    for (int m = 0; m < 16; ++m)
      asm volatile("" : "+v"(w[m].x), "+v"(w[m].y), "+v"(w[m].z), "+v"(w[m].w));

    const int par = s & 1;
    const uint32_t tag = (uint32_t)((s + 1) & 0xffff);
    const float dval = fsb[s];
    float g = 0.f, gq1 = 0.f, gq2 = 0.f, gq3 = 0.f, ufn = 0.f;

    if (t < 64) {
      // prefetch U(s+1) (clamped: rows >= len are poison) + 4 gates,
      // all during the peers' poll window -> off the serial chain
      int sn = (s + 1 < len) ? (s + 1) : s;
      ufn = (float)Ub[(size_t)sn * HH + 64 * p + t];
      g   = 1.f / (1.f + __expf(0.f - dval));  // n=0 (own h-gate too)
      gq1 = 1.f / (1.f + __expf(3.f - dval));
      gq2 = 1.f / (1.f + __expf(6.f - dval));
      gq3 = 1.f / (1.f + __expf(9.f - dval));
    } else if (t < 256) {
      g = 1.f / (1.f + __expf((float)(3 * n) - dval));
      // waves 1..3: each gathers one peer's 64 self-tagged dwords.
      // Their vmcnt stream contains ONLY poll loads (weight loads drained
      // pre-loop) -> each poll waits on its own load only.
      int wv = t >> 6;       // 1,2,3
      int lane = t & 63;
      int q = (p + wv) & 3;  // peer CU
      uint32_t* addr = &Cex[((par * 64 + b) * 4 + q) * 64 + lane];
      uint32_t dw;
      do {
        dw = __hip_atomic_load(addr, __ATOMIC_RELAXED,
                               __HIP_MEMORY_SCOPE_AGENT);
      } while ((dw & 0xffffu) != tag);
      cbuf[64 * q + lane] =
          __builtin_bit_cast(f16, (unsigned short)(dw >> 16));
    }
    __syncthreads();  // B1: full c(s) in cbuf

    // matvec: thread covers (n, o_loc) x 128 inputs; weights in registers,
    // ap wave-uniform LDS broadcast.
    float acc = 0.f;
    const uint4* ap = cvec + ch2 * 16;
#pragma unroll
    for (int m = 0; m < 16; ++m) acc = dot8(w[m], ap[m], acc);
    partials[t] = acc;  // t = ch2*256 + out_i

    // h-update off the serial chain (reads own-region c(s); own region is
    // only overwritten post-B2)
    if (t < 256) {
      float cown = (float)cbuf[64 * p + o_loc];
      h = g * cown + (1.f - g) * h;
    }
    __syncthreads();  // B2: partials complete

    if (t < 64) {
      float w0 = partials[t]       + partials[256 + t];
      float w1 = partials[64 + t]  + partials[320 + t];
      float w2 = partials[128 + t] + partials[384 + t];
      float w3 = partials[192 + t] + partials[448 + t];
      v0 = g   * w0 + (1.f - g)   * v0;
      v1 = gq1 * w1 + (1.f - gq1) * v1;
      v2 = gq2 * w2 + (1.f - gq2) * v2;
      v3 = gq3 * w3 + (1.f - gq3) * v3;
      float c = fast_tanh(ufn + (v0 + v1 + v2 + v3));
      f16 chv = (f16)c;
      uint32_t dwp =
          ((uint32_t)__builtin_bit_cast(unsigned short, chv) << 16) |
          (uint32_t)((s + 2) & 0xffff);
      __hip_atomic_store(
          &Cex[(((s + 1) & 1) * 64 + b) * 256 + p * 64 + t], dwp,
          __ATOMIC_RELAXED, __HIP_MEMORY_SCOPE_AGENT);
      cbuf[64 * p + t] = chv;  // next-iter matvec reads after B1
    }
    // no B3: peer-region cbuf rewrites (next iter, pre-B1) only race with
    // reads that completed before B2; own-region rewrite is post-B2.
  }

  // ---- epilogue: fc1 partial over this CU's 256 k's, then one-time sync
  if (t < 256) hbuf[out_i] = h;  // hbuf[k_loc]: n=k_loc>>6, i=64p+(k_loc&63)
  __syncthreads();
  {
    float acc = 0.f;
#pragma unroll 4
    for (int r = 0; r < 128; ++r) {
      int k_loc = ch2 * 128 + r;
      int n2 = k_loc >> 6, il = k_loc & 63;
      int kg = n2 * 256 + 64 * p + il;
      acc += hbuf[k_loc] * fc1T[(size_t)kg * 256 + out_i];
    }
    partials[t] = acc;
  }
  __syncthreads();
  if (t < 256) FPg[(b * 4 + p) * 256 + out_i] =
      partials[out_i] + partials[256 + out_i];
  __syncthreads();  // barrier drains stores before flag
  if (t == 0)
    __hip_atomic_store(&Flg[b * 4 + p], 0x5A5A5A5A, __ATOMIC_RELEASE,
                       __HIP_MEMORY_SCOPE_AGENT);
  if (p != 0) return;
  if (t < 4 && t > 0) {
    while (__hip_atomic_load(&Flg[b * 4 + t], __ATOMIC_ACQUIRE,
                             __HIP_MEMORY_SCOPE_AGENT) != 0x5A5A5A5A) {
    }
  }
  __syncthreads();
  if (t < 256) {
    float pre = fc1_b[t];
#pragma unroll
    for (int q = 0; q < 4; ++q)
      pre += __hip_atomic_load(&FPg[(b * 4 + q) * 256 + t], __ATOMIC_RELAXED,
                               __HIP_MEMORY_SCOPE_AGENT);
    hbuf[t] = fast_tanh(pre);  // reuse as hid
  }
  __syncthreads();
  if (t < 64) {
    float p0 = 0.f, p1 = 0.f;
    for (int oi = t; oi < 256; oi += 64) {
      float hh = hbuf[oi];
      p0 += hh * fc2_W[oi];
      p1 += hh * fc2_W[256 + oi];
    }
#pragma unroll
    for (int off = 32; off; off >>= 1) {
      p0 += __shfl_down(p0, off);
      p1 += __shfl_down(p1, off);
    }
    if (t == 0) {
      out[b * 2 + 0] = p0 + fc2_b[0];
      out[b * 2 + 1] = p1 + fc2_b[1];
    }
  }
}

// ---------------------------------------------------------------------------
// Host launcher
// ws: [0,512K) Wq | [512K,768K) WiT | [768K,1792K) fc1T | [1792K,18176K) U
//     | [18176K,18304K) Cex | [18304K,18560K) FPg | [18560K,+1K) Flg
// Cex/Flg need no init: 0xAA poison never matches a tag (0xAAAA>512) or the
// 0x5A5A5A5A magic.
// ---------------------------------------------------------------------------
extern "C" void kernel_launch(void* const* d_in, const int* in_sizes, int n_in,
                              void* d_out, int out_size, void* d_ws, size_t ws_size,
                              hipStream_t stream) {
  const int* src = (const int*)d_in[0];
  const int* input_len = (const int*)d_in[1];
  const float* fix_src = (const float*)d_in[2];
  const float* emb = (const float*)d_in[3];
  const float* Wi = (const float*)d_in[4];
  const float* bi = (const float*)d_in[5];
  const float* Wh = (const float*)d_in[6];
  const float* bh = (const float*)d_in[7];
  const float* fc1_W = (const float*)d_in[8];
  const float* fc1_b = (const float*)d_in[9];
  const float* fc2_W = (const float*)d_in[10];
  const float* fc2_b = (const float*)d_in[11];
  float* out = (float*)d_out;

  char* ws = (char*)d_ws;
  uint4* Wq = (uint4*)(ws);                          // 512 KB
  float* WiT = (float*)(ws + (512ull << 10));        // 256 KB
  float* fc1T = (float*)(ws + (768ull << 10));       // 1 MB
  f16* U = (f16*)(ws + (1792ull << 10));             // 16 MB
  uint32_t* Cex = (uint32_t*)(ws + (18176ull << 10)); // 128 KB
  float* FPg = (float*)(ws + (18304ull << 10));      // 256 KB
  int* Flg = (int*)(ws + (18560ull << 10));          // 1 KB
  const size_t needed = (18561ull << 10);
  if (ws_size < needed) return;

  // one-time: allow large dynamic LDS for k_recurrence (host-side, safe
  // under graph capture)
  static bool attr_set = false;
  if (!attr_set) {
    hipFuncSetAttribute((const void*)k_recurrence,
                        hipFuncAttributeMaxDynamicSharedMemorySize, RECUR_LDS);
    attr_set = true;
  }

  k_pack_wq<<<128, 256, 0, stream>>>(Wh, Wq);
  k_transpose8<<<(65536 + 255) / 256, 256, 0, stream>>>(Wi, WiT, 256, 65536);
  k_transpose8<<<(262144 + 255) / 256, 256, 0, stream>>>(fc1_W, fc1T, 1024, 262144);
  k_precompute_u<<<BB * SS / 32, 256, 0, stream>>>(src, emb, WiT, bi, bh,
                                                   input_len, U);
  k_recurrence<<<BB * 4, TT, RECUR_LDS, stream>>>(Wq, U, fix_src, input_len,
                                                  fc1T, fc1_b, fc2_W, fc2_b,
                                                  out, Cex, FPg, Flg);
}

// Round 5
// 777.565 us; speedup vs baseline: 1.0732x; 1.0153x over previous
//
#include <hip/hip_runtime.h>
#include <stdint.h>

// Problem constants
constexpr int BB = 64;     // batch
constexpr int SS = 512;    // seq len
constexpr int DD = 256;    // emb dim
constexpr int HH = 256;    // hidden
constexpr int NHH = 4;     // heads
constexpr int KK = 1024;   // NH*H recurrent input dim

// HARD FACTS (r2-r14):
//  - Step time == streamed_weight_bytes / 64 B/cyc when weights come from
//    L2 (r7; R11: 2048+640 cyc exactly). All-LDS weights = 2176 cyc/step
//    through the single LDS pipe (R12, regression). Relaxed self-tagged
//    exchange chain = 640 cyc/step (R11).
//  - R14: asm-opaque loads + DYNAMIC LDS spilled 64 weight VGPRs to
//    scratch (VGPR=56): unknown dynamic-LDS size => backend assumes LDS=0
//    => targets 8 waves/EU => clamps pressure at 64 => spill. The
//    waves_per_eu MIN only sets the budget; the MAX sets the scheduler's
//    occupancy target.
//
// ROUND 15: same kernel as R14 with the two-part no-spill fix:
//  (a) amdgpu_waves_per_eu(2, 2) -- max=2 pins the occupancy target, so
//      pressure up to 256 VGPRs is acceptable to the scheduler;
//  (b) STATIC 60 KB LDS arena -- compile-time-visible => occupancy
//      ceiling 2 WG/CU = 4 waves/EU => VGPR target 128 >= demand ~110,
//      an independent second path to no-spill (R10/R11 at this target
//      didn't spill; they rematerialized plain loads -- asm loads can't
//      be rematerialized, so they must stay resident).
// Weight traffic per step: ZERO. Step = chain(640) + ap uniform reads
// (640) + dot/tail(~300) ~= 1500-1900 cyc ~= 625-790 ns.
// Schedule/exchange/epilogue = R11 (2 barriers, fence-free self-tagged
// parity exchange; race audit unchanged).
constexpr int TT = 512;

typedef _Float16 f16;
typedef _Float16 f16x2 __attribute__((ext_vector_type(2)));

__device__ inline float dot2p(uint32_t a, uint32_t b, float c) {
  f16x2 av = __builtin_bit_cast(f16x2, a);
  f16x2 bv = __builtin_bit_cast(f16x2, b);
#if defined(__has_builtin)
#if __has_builtin(__builtin_amdgcn_fdot2)
  return __builtin_amdgcn_fdot2(av, bv, c, false);
#else
  return c + (float)av.x * (float)bv.x + (float)av.y * (float)bv.y;
#endif
#else
  return c + (float)av.x * (float)bv.x + (float)av.y * (float)bv.y;
#endif
}

__device__ inline float dot8(uint4 w, uint4 a, float c) {
  c = dot2p(w.x, a.x, c);
  c = dot2p(w.y, a.y, c);
  c = dot2p(w.z, a.z, c);
  c = dot2p(w.w, a.w, c);
  return c;
}

__device__ inline uint32_t pack2(float a, float b) {
  f16x2 v;
  v.x = (f16)a;
  v.y = (f16)b;
  return __builtin_bit_cast(uint32_t, v);
}

__device__ inline float fast_tanh(float x) {
  x = fminf(fmaxf(x, -15.f), 15.f);
  float e = __expf(2.f * x);
  return 1.f - 2.f / (e + 1.f);
}

// ---------------------------------------------------------------------------
// Prep A1: pack Wh [256,1024] fp32 -> Wq f16 for the v-form matvec.
// Wq[(p*16 + m)*512 + t] (slot-major): t -> out=t&255 (n=out>>6,
// o_loc=out&63), ch2=t>>8. Holds Wh[64p + o_loc][256n + 128*ch2 + 8m .. +8)
// as 8 packed f16. Slot-major => one-time register load is perfectly
// coalesced (lane-contiguous uint4 per slot).
// ---------------------------------------------------------------------------
__global__ void k_pack_wq(const float* __restrict__ Wh, uint4* __restrict__ Wq) {
  int gid = blockIdx.x * blockDim.x + threadIdx.x;  // 32768
  int p = gid >> 13;
  int m = (gid >> 9) & 15;
  int t = gid & 511;
  int out = t & 255, ch2 = t >> 8;
  int n = out >> 6, o_loc = out & 63;
  const float* s = Wh + (64 * p + o_loc) * KK + 256 * n + 128 * ch2 + 8 * m;
  uint4 w;
  w.x = pack2(s[0], s[1]);
  w.y = pack2(s[2], s[3]);
  w.z = pack2(s[4], s[5]);
  w.w = pack2(s[6], s[7]);
  Wq[gid] = w;
}

// ---------------------------------------------------------------------------
// Prep A2/A3: transpose src[r, C] (r in [0,256)) -> dst[c*256 + r]
// ---------------------------------------------------------------------------
__global__ void k_transpose8(const float* __restrict__ src, float* __restrict__ dst,
                             int C, int total) {
  int gid = blockIdx.x * blockDim.x + threadIdx.x;
  if (gid >= total) return;
  int r = gid & 255, c = gid >> 8;
  dst[gid] = src[r * C + c];
}

// ---------------------------------------------------------------------------
// Prep B: U[row, o] = emb[src[row]] @ Wi^T + bi + bh (f16). Blocks beyond
// input_len[b] skipped.
// ---------------------------------------------------------------------------
__global__ __launch_bounds__(256) void k_precompute_u(
    const int* __restrict__ src, const float* __restrict__ emb,
    const float* __restrict__ WiT, const float* __restrict__ bi,
    const float* __restrict__ bh, const int* __restrict__ input_len,
    f16* __restrict__ U) {
  const int row0 = blockIdx.x * 32;
  const int b = row0 >> 9;
  if ((row0 & 511) >= input_len[b]) return;
  __shared__ float xs[32 * 256];
  __shared__ int srcs[32];
  const int tid = threadIdx.x;
  if (tid < 32) srcs[tid] = src[row0 + tid];
  __syncthreads();
  for (int i = tid; i < 32 * 256; i += 256) {
    int r = i >> 8, d = i & 255;
    xs[i] = emb[srcs[r] * DD + d];
  }
  __syncthreads();
  const int o = tid;
  float acc[32];
#pragma unroll
  for (int r = 0; r < 32; ++r) acc[r] = 0.f;
  for (int d0 = 0; d0 < 256; d0 += 8) {
    float w[8];
#pragma unroll
    for (int j = 0; j < 8; ++j) w[j] = WiT[(d0 + j) * 256 + o];  // coalesced
#pragma unroll
    for (int r = 0; r < 32; ++r) {
      const float4* xp = (const float4*)(xs + r * 256 + d0);  // broadcast
      float4 x0 = xp[0], x1 = xp[1];
      acc[r] += x0.x * w[0] + x0.y * w[1] + x0.z * w[2] + x0.w * w[3] +
                x1.x * w[4] + x1.y * w[5] + x1.z * w[6] + x1.w * w[7];
    }
  }
  float bias = bi[o] + bh[o];
#pragma unroll
  for (int r = 0; r < 32; ++r)
    U[(size_t)(row0 + r) * HH + o] = (f16)(acc[r] + bias);
}

// ---------------------------------------------------------------------------
// Main recurrence (v-form): 4 WGs (512 thr) per batch, blockIdx = p*64 + b
// (same-XCD heuristic; correctness is placement-independent). Thread t:
// out = t&255 (n=out>>6, o_loc=out&63), ch2 = t>>8 (input half).
// Weights: 16 uint4/thread, loaded ONCE via opaque asm loads -> VGPRs for
// the whole kernel. Static 60 KB arena (compiler sees 2-WG class -> VGPR
// target 128 >= demand ~110) + waves_per_eu(2,2) (occupancy target pinned
// at 2 waves/EU -> pressure up to 256 acceptable): no spill, no remat.
// Per-step weight traffic: zero.
// Per-step schedule (2 barriers):
//   [poll window] wave0: prefetch U(s+1), 4 gates | waves1-3: gather c(s)
//   B1 | all: matvec (reg weights, LDS ap) -> partials; t<256: h-update
//   B2 | wave0: v-update (regs) -> z -> c(s+1) -> publish + cbuf write
// ---------------------------------------------------------------------------
__global__ void __attribute__((amdgpu_flat_work_group_size(512, 512),
                               amdgpu_waves_per_eu(2, 2)))
k_recurrence(
    const uint4* __restrict__ Wq, const f16* __restrict__ U,
    const float* __restrict__ fix_src, const int* __restrict__ input_len,
    const float* __restrict__ fc1T, const float* __restrict__ fc1_b,
    const float* __restrict__ fc2_W, const float* __restrict__ fc2_b,
    float* __restrict__ out, uint32_t* __restrict__ Cex,
    float* __restrict__ FPg, int* __restrict__ Flg) {
  __shared__ __align__(16) char arena[61440];  // 60 KB -> 2-WG class
  f16* cbuf = (f16*)arena;                    // [0,512): c as f16[256]
  uint4* cvec = (uint4*)arena;                // same bytes, 32 uint4
  float* partials = (float*)(arena + 512);    // [512,2560): 512 floats
  float* hbuf = (float*)(arena + 2560);       // [2560,3584): 256 floats

  const int idx = blockIdx.x;
  const int b = idx & 63;
  const int p = idx >> 6;
  const int t = threadIdx.x;
  const int out_i = t & 255, ch2 = t >> 8;
  const int n = out_i >> 6, o_loc = out_i & 63;

  // one-time: this CU's 128 KB weight slab -> 64 VGPRs via OPAQUE asm
  // loads. The compiler cannot rematerialize asm outputs; with pressure
  // (~110) under the target (128 static-LDS path / 256 waves_per_eu path)
  // it has no reason to spill them either.
  uint4 w[16];
  {
    const uint4* wp = Wq + (p * 16) * TT + t;
#pragma unroll
    for (int m = 0; m < 16; ++m) {
      const uint4* a = wp + m * TT;
      asm volatile("global_load_dwordx4 %0, %1, off"
                   : "=v"(w[m]) : "v"(a) : "memory");
    }
    asm volatile("s_waitcnt vmcnt(0)" ::: "memory");
  }

  // wave0 register state: v_n[64p + lane] for n=0..3
  float v0 = 0.f, v1 = 0.f, v2 = 0.f, v3 = 0.f;
  float h = 0.f;  // h_n[64p + o_loc] on threads t<256

  const int len = input_len[b];
  const f16* Ub = U + (size_t)b * SS * HH;
  const float* fsb = fix_src + b * SS;

  // prologue: c(0) = tanh(U(0)), publish slot 0 / tag 1. Own-region cbuf
  // write is ordered before the first matvec by B1 of iteration 0.
  if (t < 64) {
    float c0 = fast_tanh((float)Ub[64 * p + t]);
    f16 chv = (f16)c0;
    cbuf[64 * p + t] = chv;
    uint32_t dwp =
        ((uint32_t)__builtin_bit_cast(unsigned short, chv) << 16) | 1u;
    __hip_atomic_store(&Cex[b * 256 + p * 64 + t], dwp, __ATOMIC_RELAXED,
                       __HIP_MEMORY_SCOPE_AGENT);
  }

#pragma unroll 1
  for (int s = 0; s < len; ++s) {
    // residency pin: w[] must be live-in to every iteration in VGPRs.
    // Per-32-bit-component ties only -- uint4 "+v" does not compile.
#pragma unroll
    for (int m = 0; m < 16; ++m)
      asm volatile("" : "+v"(w[m].x), "+v"(w[m].y), "+v"(w[m].z), "+v"(w[m].w));

    const int par = s & 1;
    const uint32_t tag = (uint32_t)((s + 1) & 0xffff);
    const float dval = fsb[s];
    float g = 0.f, gq1 = 0.f, gq2 = 0.f, gq3 = 0.f, ufn = 0.f;

    if (t < 64) {
      // prefetch U(s+1) (clamped: rows >= len are poison) + 4 gates,
      // all during the peers' poll window -> off the serial chain
      int sn = (s + 1 < len) ? (s + 1) : s;
      ufn = (float)Ub[(size_t)sn * HH + 64 * p + t];
      g   = 1.f / (1.f + __expf(0.f - dval));  // n=0 (own h-gate too)
      gq1 = 1.f / (1.f + __expf(3.f - dval));
      gq2 = 1.f / (1.f + __expf(6.f - dval));
      gq3 = 1.f / (1.f + __expf(9.f - dval));
    } else if (t < 256) {
      g = 1.f / (1.f + __expf((float)(3 * n) - dval));
      // waves 1..3: each gathers one peer's 64 self-tagged dwords.
      int wv = t >> 6;       // 1,2,3
      int lane = t & 63;
      int q = (p + wv) & 3;  // peer CU
      uint32_t* addr = &Cex[((par * 64 + b) * 4 + q) * 64 + lane];
      uint32_t dw;
      do {
        dw = __hip_atomic_load(addr, __ATOMIC_RELAXED,
                               __HIP_MEMORY_SCOPE_AGENT);
      } while ((dw & 0xffffu) != tag);
      cbuf[64 * q + lane] =
          __builtin_bit_cast(f16, (unsigned short)(dw >> 16));
    }
    __syncthreads();  // B1: full c(s) in cbuf

    // matvec: thread covers (n, o_loc) x 128 inputs; weights in registers,
    // ap wave-uniform LDS broadcast.
    float acc = 0.f;
    const uint4* ap = cvec + ch2 * 16;
#pragma unroll
    for (int m = 0; m < 16; ++m) acc = dot8(w[m], ap[m], acc);
    partials[t] = acc;  // t = ch2*256 + out_i

    // h-update off the serial chain (reads own-region c(s); own region is
    // only overwritten post-B2)
    if (t < 256) {
      float cown = (float)cbuf[64 * p + o_loc];
      h = g * cown + (1.f - g) * h;
    }
    __syncthreads();  // B2: partials complete

    if (t < 64) {
      float w0 = partials[t]       + partials[256 + t];
      float w1 = partials[64 + t]  + partials[320 + t];
      float w2 = partials[128 + t] + partials[384 + t];
      float w3 = partials[192 + t] + partials[448 + t];
      v0 = g   * w0 + (1.f - g)   * v0;
      v1 = gq1 * w1 + (1.f - gq1) * v1;
      v2 = gq2 * w2 + (1.f - gq2) * v2;
      v3 = gq3 * w3 + (1.f - gq3) * v3;
      float c = fast_tanh(ufn + (v0 + v1 + v2 + v3));
      f16 chv = (f16)c;
      uint32_t dwp =
          ((uint32_t)__builtin_bit_cast(unsigned short, chv) << 16) |
          (uint32_t)((s + 2) & 0xffff);
      __hip_atomic_store(
          &Cex[(((s + 1) & 1) * 64 + b) * 256 + p * 64 + t], dwp,
          __ATOMIC_RELAXED, __HIP_MEMORY_SCOPE_AGENT);
      cbuf[64 * p + t] = chv;  // next-iter matvec reads after B1
    }
    // no B3: peer-region cbuf rewrites (next iter, pre-B1) only race with
    // reads that completed before B2; own-region rewrite is post-B2.
  }

  // ---- epilogue: fc1 partial over this CU's 256 k's, then one-time sync
  if (t < 256) hbuf[out_i] = h;  // hbuf[k_loc]: n=k_loc>>6, i=64p+(k_loc&63)
  __syncthreads();
  {
    float acc = 0.f;
#pragma unroll 4
    for (int r = 0; r < 128; ++r) {
      int k_loc = ch2 * 128 + r;
      int n2 = k_loc >> 6, il = k_loc & 63;
      int kg = n2 * 256 + 64 * p + il;
      acc += hbuf[k_loc] * fc1T[(size_t)kg * 256 + out_i];
    }
    partials[t] = acc;
  }
  __syncthreads();
  if (t < 256) FPg[(b * 4 + p) * 256 + out_i] =
      partials[out_i] + partials[256 + out_i];
  __syncthreads();  // barrier drains stores before flag
  if (t == 0)
    __hip_atomic_store(&Flg[b * 4 + p], 0x5A5A5A5A, __ATOMIC_RELEASE,
                       __HIP_MEMORY_SCOPE_AGENT);
  if (p != 0) return;
  if (t < 4 && t > 0) {
    while (__hip_atomic_load(&Flg[b * 4 + t], __ATOMIC_ACQUIRE,
                             __HIP_MEMORY_SCOPE_AGENT) != 0x5A5A5A5A) {
    }
  }
  __syncthreads();
  if (t < 256) {
    float pre = fc1_b[t];
#pragma unroll
    for (int q = 0; q < 4; ++q)
      pre += __hip_atomic_load(&FPg[(b * 4 + q) * 256 + t], __ATOMIC_RELAXED,
                               __HIP_MEMORY_SCOPE_AGENT);
    hbuf[t] = fast_tanh(pre);  // reuse as hid
  }
  __syncthreads();
  if (t < 64) {
    float p0 = 0.f, p1 = 0.f;
    for (int oi = t; oi < 256; oi += 64) {
      float hh = hbuf[oi];
      p0 += hh * fc2_W[oi];
      p1 += hh * fc2_W[256 + oi];
    }
#pragma unroll
    for (int off = 32; off; off >>= 1) {
      p0 += __shfl_down(p0, off);
      p1 += __shfl_down(p1, off);
    }
    if (t == 0) {
      out[b * 2 + 0] = p0 + fc2_b[0];
      out[b * 2 + 1] = p1 + fc2_b[1];
    }
  }
}

// ---------------------------------------------------------------------------
// Host launcher
// ws: [0,512K) Wq | [512K,768K) WiT | [768K,1792K) fc1T | [1792K,18176K) U
//     | [18176K,18304K) Cex | [18304K,18560K) FPg | [18560K,+1K) Flg
// Cex/Flg need no init: 0xAA poison never matches a tag (0xAAAA>512) or the
// 0x5A5A5A5A magic.
// ---------------------------------------------------------------------------
extern "C" void kernel_launch(void* const* d_in, const int* in_sizes, int n_in,
                              void* d_out, int out_size, void* d_ws, size_t ws_size,
                              hipStream_t stream) {
  const int* src = (const int*)d_in[0];
  const int* input_len = (const int*)d_in[1];
  const float* fix_src = (const float*)d_in[2];
  const float* emb = (const float*)d_in[3];
  const float* Wi = (const float*)d_in[4];
  const float* bi = (const float*)d_in[5];
  const float* Wh = (const float*)d_in[6];
  const float* bh = (const float*)d_in[7];
  const float* fc1_W = (const float*)d_in[8];
  const float* fc1_b = (const float*)d_in[9];
  const float* fc2_W = (const float*)d_in[10];
  const float* fc2_b = (const float*)d_in[11];
  float* out = (float*)d_out;

  char* ws = (char*)d_ws;
  uint4* Wq = (uint4*)(ws);                          // 512 KB
  float* WiT = (float*)(ws + (512ull << 10));        // 256 KB
  float* fc1T = (float*)(ws + (768ull << 10));       // 1 MB
  f16* U = (f16*)(ws + (1792ull << 10));             // 16 MB
  uint32_t* Cex = (uint32_t*)(ws + (18176ull << 10)); // 128 KB
  float* FPg = (float*)(ws + (18304ull << 10));      // 256 KB
  int* Flg = (int*)(ws + (18560ull << 10));          // 1 KB
  const size_t needed = (18561ull << 10);
  if (ws_size < needed) return;

  k_pack_wq<<<128, 256, 0, stream>>>(Wh, Wq);
  k_transpose8<<<(65536 + 255) / 256, 256, 0, stream>>>(Wi, WiT, 256, 65536);
  k_transpose8<<<(262144 + 255) / 256, 256, 0, stream>>>(fc1_W, fc1T, 1024, 262144);
  k_precompute_u<<<BB * SS / 32, 256, 0, stream>>>(src, emb, WiT, bi, bh,
                                                   input_len, U);
  k_recurrence<<<BB * 4, TT, 0, stream>>>(Wq, U, fix_src, input_len, fc1T,
                                          fc1_b, fc2_W, fc2_b, out, Cex, FPg,
                                          Flg);
}

// Round 6
// 719.862 us; speedup vs baseline: 1.1592x; 1.0802x over previous
//
#include <hip/hip_runtime.h>
#include <stdint.h>

// Problem constants
constexpr int BB = 64;     // batch
constexpr int SS = 512;    // seq len
constexpr int DD = 256;    // emb dim
constexpr int HH = 256;    // hidden
constexpr int NHH = 4;     // heads
constexpr int KK = 1024;   // NH*H recurrent input dim

// HARD FACTS (r2-r15):
//  - R15 closed the residency question: VGPR=88 = 64 weight regs + ~24
//    live set -> weights fully resident (asm-opaque loads + static 60KB
//    LDS class + waves_per_eu(2,2)). Time 573->576us vs streamed R11:
//    weight location is IRRELEVANT -- r7's streaming law was masking the
//    real floor.
//  - Step floor (~2700cyc = 1.12us) = agent-scope publish->LLC->poll
//    (~600-1000cyc; agent atomics round-trip the device coherence point)
//    + 128 uniform LDS b128 broadcasts (~640cyc, one pipe/CU) + matvec
//    VALU (~300cyc) + barriers.
//  - Consolidation is impossible: 512KB weights > 1024 thr x 64 VGPR =
//    256KB (1-WG) and > LDS 160KB; MFMA-batched streams 512KB/step.
//  - Exchange chain: relaxed self-tagged parity protocol, race-audited
//    (R10-R15, no failures). fp8/int8 weights break accuracy (r8).
//
// ROUND 16: leave k_recurrence EXACTLY as R15 (proven, 576us). Attack the
// stable ~190-200us of non-recurrence time: k_precompute_u was a 4.3GFLOP
// GEMM done as a VALU loop with ~2048 wave-uniform LDS broadcasts/thread
// (single LDS pipe per CU -> ~150us). Replace with f16 MFMA tiled GEMM
// (16x16x32_f16): A = emb rows staged to LDS with T2 XOR swizzle
// (^((row&7)<<4)) breaking the 16-way stride-512B conflict; B = f16 copy
// of Wi read as contiguous b128 (L2-hot); D layout col=l&15,
// row=(l>>4)*4+reg (m89-verified, dtype-independent). f16 input error
// ~1e-4 << existing 2^-9 absmax from f16 Wq.
constexpr int TT = 512;

typedef _Float16 f16;
typedef _Float16 f16x2 __attribute__((ext_vector_type(2)));
typedef _Float16 half8 __attribute__((ext_vector_type(8)));
typedef float f32x4 __attribute__((ext_vector_type(4)));

__device__ inline float dot2p(uint32_t a, uint32_t b, float c) {
  f16x2 av = __builtin_bit_cast(f16x2, a);
  f16x2 bv = __builtin_bit_cast(f16x2, b);
#if defined(__has_builtin)
#if __has_builtin(__builtin_amdgcn_fdot2)
  return __builtin_amdgcn_fdot2(av, bv, c, false);
#else
  return c + (float)av.x * (float)bv.x + (float)av.y * (float)bv.y;
#endif
#else
  return c + (float)av.x * (float)bv.x + (float)av.y * (float)bv.y;
#endif
}

__device__ inline float dot8(uint4 w, uint4 a, float c) {
  c = dot2p(w.x, a.x, c);
  c = dot2p(w.y, a.y, c);
  c = dot2p(w.z, a.z, c);
  c = dot2p(w.w, a.w, c);
  return c;
}

__device__ inline uint32_t pack2(float a, float b) {
  f16x2 v;
  v.x = (f16)a;
  v.y = (f16)b;
  return __builtin_bit_cast(uint32_t, v);
}

__device__ inline float fast_tanh(float x) {
  x = fminf(fmaxf(x, -15.f), 15.f);
  float e = __expf(2.f * x);
  return 1.f - 2.f / (e + 1.f);
}

// ---------------------------------------------------------------------------
// Prep A1: pack Wh [256,1024] fp32 -> Wq f16 for the v-form matvec.
// Wq[(p*16 + m)*512 + t] (slot-major): t -> out=t&255 (n=out>>6,
// o_loc=out&63), ch2=t>>8. Holds Wh[64p + o_loc][256n + 128*ch2 + 8m .. +8)
// as 8 packed f16.
// ---------------------------------------------------------------------------
__global__ void k_pack_wq(const float* __restrict__ Wh, uint4* __restrict__ Wq) {
  int gid = blockIdx.x * blockDim.x + threadIdx.x;  // 32768
  int p = gid >> 13;
  int m = (gid >> 9) & 15;
  int t = gid & 511;
  int out = t & 255, ch2 = t >> 8;
  int n = out >> 6, o_loc = out & 63;
  const float* s = Wh + (64 * p + o_loc) * KK + 256 * n + 128 * ch2 + 8 * m;
  uint4 w;
  w.x = pack2(s[0], s[1]);
  w.y = pack2(s[2], s[3]);
  w.z = pack2(s[4], s[5]);
  w.w = pack2(s[6], s[7]);
  Wq[gid] = w;
}

// ---------------------------------------------------------------------------
// Prep A2: transpose src[r, C] (r in [0,256)) -> dst[c*256 + r] (fc1T)
// ---------------------------------------------------------------------------
__global__ void k_transpose8(const float* __restrict__ src, float* __restrict__ dst,
                             int C, int total) {
  int gid = blockIdx.x * blockDim.x + threadIdx.x;
  if (gid >= total) return;
  int r = gid & 255, c = gid >> 8;
  dst[gid] = src[r * C + c];
}

// ---------------------------------------------------------------------------
// Prep A3: Wi f32 [256 o][256 d] -> f16 same layout (B-operand for U GEMM)
// ---------------------------------------------------------------------------
__global__ void k_cvt_f16(const float* __restrict__ src, f16* __restrict__ dst,
                          int total) {
  int gid = blockIdx.x * blockDim.x + threadIdx.x;
  if (gid >= total) return;
  dst[gid] = (f16)src[gid];
}

// ---------------------------------------------------------------------------
// Prep B (MFMA): U[row, o] = emb[src[row]] @ Wi^T + bi + bh, f16 out.
// Tile: 64 rows x 256 cols per WG (256 thr, 4 waves; wave w -> rows
// w*16..+16). A staged in LDS as f16 [64][256] with byte-XOR swizzle
// ^((row&7)<<4) (2-way residual conflict = free, m136). B-frags read
// straight from wif (f16 Wi, row-major in d -> contiguous b128, L2-hot).
// mfma_f32_16x16x32_f16 frags: A lane: row=l&15, k=(l>>4)*8+e (contig);
// B lane: col=l&15, k=(l>>4)*8+e (contig in d of Wi[o][d]); D: col=l&15,
// row=(l>>4)*4+reg (m89-verified). Blocks fully beyond input_len skipped.
// ---------------------------------------------------------------------------
__global__ __launch_bounds__(256) void k_u_mfma(
    const int* __restrict__ src, const float* __restrict__ emb,
    const f16* __restrict__ wif, const float* __restrict__ bi,
    const float* __restrict__ bh, const int* __restrict__ input_len,
    f16* __restrict__ U) {
  __shared__ __align__(16) char xls[32768];  // 64 rows x 512 B
  const int row0 = blockIdx.x * 64;
  const int b = row0 >> 9;
  if ((row0 & 511) >= input_len[b]) return;
  const int t = threadIdx.x;
  const int w = t >> 6, l = t & 63;

  // stage: wave w gathers its 16 rows (f32 -> f16), swizzled LDS write
  for (int rr = 0; rr < 16; ++rr) {
    int r = w * 16 + rr;                    // LDS row 0..63
    int srcid = src[row0 + r];              // uniform -> s_load
    const float4 x = *(const float4*)(emb + (size_t)srcid * DD + l * 4);
    uint2 dw;
    dw.x = pack2(x.x, x.y);
    dw.y = pack2(x.z, x.w);
    int byte = (r * 512 + l * 8) ^ ((r & 7) << 4);
    *(uint2*)(xls + byte) = dw;
  }
  __syncthreads();

  const int lm = l & 15, lk = l >> 4;
  const int arow = w * 16 + lm;             // A row for this lane
  const int xs = (arow & 7) << 4;           // swizzle bits

  for (int ct = 0; ct < 16; ++ct) {
    const int o = ct * 16 + lm;             // B col / D col
    f32x4 acc = {0.f, 0.f, 0.f, 0.f};
    const f16* bp = wif + (size_t)o * 256 + lk * 8;
#pragma unroll
    for (int kt = 0; kt < 8; ++kt) {
      int ab = (arow * 512 + kt * 64 + lk * 16) ^ xs;
      half8 af = *(const half8*)(xls + ab);
      half8 bf = *(const half8*)(bp + kt * 32);
      acc = __builtin_amdgcn_mfma_f32_16x16x32_f16(af, bf, acc, 0, 0, 0);
    }
    float bias = bi[o] + bh[o];
#pragma unroll
    for (int reg = 0; reg < 4; ++reg) {
      int grow = row0 + w * 16 + lk * 4 + reg;  // D row
      U[(size_t)grow * HH + o] = (f16)(acc[reg] + bias);
    }
  }
}

// ---------------------------------------------------------------------------
// Main recurrence (v-form): UNCHANGED from R15 (proven: VGPR=88 = full
// weight residency; 576us; floor = LLC exchange + LDS broadcast + VALU).
// 4 WGs (512 thr) per batch, blockIdx = p*64 + b. Thread t: out=t&255
// (n=out>>6, o_loc=out&63), ch2=t>>8. Weights: 16 uint4/thread via opaque
// asm loads, resident all kernel. Static 60KB arena -> 2-WG class (VGPR
// target 128) + waves_per_eu(2,2).
// Per-step schedule (2 barriers):
//   [poll window] wave0: prefetch U(s+1), 4 gates | waves1-3: gather c(s)
//   B1 | all: matvec (reg weights, LDS ap) -> partials; t<256: h-update
//   B2 | wave0: v-update (regs) -> z -> c(s+1) -> publish + cbuf write
// ---------------------------------------------------------------------------
__global__ void __attribute__((amdgpu_flat_work_group_size(512, 512),
                               amdgpu_waves_per_eu(2, 2)))
k_recurrence(
    const uint4* __restrict__ Wq, const f16* __restrict__ U,
    const float* __restrict__ fix_src, const int* __restrict__ input_len,
    const float* __restrict__ fc1T, const float* __restrict__ fc1_b,
    const float* __restrict__ fc2_W, const float* __restrict__ fc2_b,
    float* __restrict__ out, uint32_t* __restrict__ Cex,
    float* __restrict__ FPg, int* __restrict__ Flg) {
  __shared__ __align__(16) char arena[61440];  // 60 KB -> 2-WG class
  f16* cbuf = (f16*)arena;                    // [0,512): c as f16[256]
  uint4* cvec = (uint4*)arena;                // same bytes, 32 uint4
  float* partials = (float*)(arena + 512);    // [512,2560): 512 floats
  float* hbuf = (float*)(arena + 2560);       // [2560,3584): 256 floats

  const int idx = blockIdx.x;
  const int b = idx & 63;
  const int p = idx >> 6;
  const int t = threadIdx.x;
  const int out_i = t & 255, ch2 = t >> 8;
  const int n = out_i >> 6, o_loc = out_i & 63;

  // one-time: this CU's 128 KB weight slab -> 64 VGPRs via OPAQUE asm
  // loads (cannot be rematerialized; pressure ~110 < target -> resident).
  uint4 w[16];
  {
    const uint4* wp = Wq + (p * 16) * TT + t;
#pragma unroll
    for (int m = 0; m < 16; ++m) {
      const uint4* a = wp + m * TT;
      asm volatile("global_load_dwordx4 %0, %1, off"
                   : "=v"(w[m]) : "v"(a) : "memory");
    }
    asm volatile("s_waitcnt vmcnt(0)" ::: "memory");
  }

  // wave0 register state: v_n[64p + lane] for n=0..3
  float v0 = 0.f, v1 = 0.f, v2 = 0.f, v3 = 0.f;
  float h = 0.f;  // h_n[64p + o_loc] on threads t<256

  const int len = input_len[b];
  const f16* Ub = U + (size_t)b * SS * HH;
  const float* fsb = fix_src + b * SS;

  // prologue: c(0) = tanh(U(0)), publish slot 0 / tag 1.
  if (t < 64) {
    float c0 = fast_tanh((float)Ub[64 * p + t]);
    f16 chv = (f16)c0;
    cbuf[64 * p + t] = chv;
    uint32_t dwp =
        ((uint32_t)__builtin_bit_cast(unsigned short, chv) << 16) | 1u;
    __hip_atomic_store(&Cex[b * 256 + p * 64 + t], dwp, __ATOMIC_RELAXED,
                       __HIP_MEMORY_SCOPE_AGENT);
  }

#pragma unroll 1
  for (int s = 0; s < len; ++s) {
    // residency pin: w[] live-in every iteration (per-component ties).
#pragma unroll
    for (int m = 0; m < 16; ++m)
      asm volatile("" : "+v"(w[m].x), "+v"(w[m].y), "+v"(w[m].z), "+v"(w[m].w));

    const int par = s & 1;
    const uint32_t tag = (uint32_t)((s + 1) & 0xffff);
    const float dval = fsb[s];
    float g = 0.f, gq1 = 0.f, gq2 = 0.f, gq3 = 0.f, ufn = 0.f;

    if (t < 64) {
      int sn = (s + 1 < len) ? (s + 1) : s;
      ufn = (float)Ub[(size_t)sn * HH + 64 * p + t];
      g   = 1.f / (1.f + __expf(0.f - dval));
      gq1 = 1.f / (1.f + __expf(3.f - dval));
      gq2 = 1.f / (1.f + __expf(6.f - dval));
      gq3 = 1.f / (1.f + __expf(9.f - dval));
    } else if (t < 256) {
      g = 1.f / (1.f + __expf((float)(3 * n) - dval));
      int wv = t >> 6;       // 1,2,3
      int lane = t & 63;
      int q = (p + wv) & 3;  // peer CU
      uint32_t* addr = &Cex[((par * 64 + b) * 4 + q) * 64 + lane];
      uint32_t dw;
      do {
        dw = __hip_atomic_load(addr, __ATOMIC_RELAXED,
                               __HIP_MEMORY_SCOPE_AGENT);
      } while ((dw & 0xffffu) != tag);
      cbuf[64 * q + lane] =
          __builtin_bit_cast(f16, (unsigned short)(dw >> 16));
    }
    __syncthreads();  // B1: full c(s) in cbuf

    float acc = 0.f;
    const uint4* ap = cvec + ch2 * 16;
#pragma unroll
    for (int m = 0; m < 16; ++m) acc = dot8(w[m], ap[m], acc);
    partials[t] = acc;  // t = ch2*256 + out_i

    if (t < 256) {
      float cown = (float)cbuf[64 * p + o_loc];
      h = g * cown + (1.f - g) * h;
    }
    __syncthreads();  // B2: partials complete

    if (t < 64) {
      float w0 = partials[t]       + partials[256 + t];
      float w1 = partials[64 + t]  + partials[320 + t];
      float w2 = partials[128 + t] + partials[384 + t];
      float w3 = partials[192 + t] + partials[448 + t];
      v0 = g   * w0 + (1.f - g)   * v0;
      v1 = gq1 * w1 + (1.f - gq1) * v1;
      v2 = gq2 * w2 + (1.f - gq2) * v2;
      v3 = gq3 * w3 + (1.f - gq3) * v3;
      float c = fast_tanh(ufn + (v0 + v1 + v2 + v3));
      f16 chv = (f16)c;
      uint32_t dwp =
          ((uint32_t)__builtin_bit_cast(unsigned short, chv) << 16) |
          (uint32_t)((s + 2) & 0xffff);
      __hip_atomic_store(
          &Cex[(((s + 1) & 1) * 64 + b) * 256 + p * 64 + t], dwp,
          __ATOMIC_RELAXED, __HIP_MEMORY_SCOPE_AGENT);
      cbuf[64 * p + t] = chv;
    }
    // no B3 (race audit: see R11 header)
  }

  // ---- epilogue: fc1 partial over this CU's 256 k's, then one-time sync
  if (t < 256) hbuf[out_i] = h;
  __syncthreads();
  {
    float acc = 0.f;
#pragma unroll 4
    for (int r = 0; r < 128; ++r) {
      int k_loc = ch2 * 128 + r;
      int n2 = k_loc >> 6, il = k_loc & 63;
      int kg = n2 * 256 + 64 * p + il;
      acc += hbuf[k_loc] * fc1T[(size_t)kg * 256 + out_i];
    }
    partials[t] = acc;
  }
  __syncthreads();
  if (t < 256) FPg[(b * 4 + p) * 256 + out_i] =
      partials[out_i] + partials[256 + out_i];
  __syncthreads();
  if (t == 0)
    __hip_atomic_store(&Flg[b * 4 + p], 0x5A5A5A5A, __ATOMIC_RELEASE,
                       __HIP_MEMORY_SCOPE_AGENT);
  if (p != 0) return;
  if (t < 4 && t > 0) {
    while (__hip_atomic_load(&Flg[b * 4 + t], __ATOMIC_ACQUIRE,
                             __HIP_MEMORY_SCOPE_AGENT) != 0x5A5A5A5A) {
    }
  }
  __syncthreads();
  if (t < 256) {
    float pre = fc1_b[t];
#pragma unroll
    for (int q = 0; q < 4; ++q)
      pre += __hip_atomic_load(&FPg[(b * 4 + q) * 256 + t], __ATOMIC_RELAXED,
                               __HIP_MEMORY_SCOPE_AGENT);
    hbuf[t] = fast_tanh(pre);
  }
  __syncthreads();
  if (t < 64) {
    float p0 = 0.f, p1 = 0.f;
    for (int oi = t; oi < 256; oi += 64) {
      float hh = hbuf[oi];
      p0 += hh * fc2_W[oi];
      p1 += hh * fc2_W[256 + oi];
    }
#pragma unroll
    for (int off = 32; off; off >>= 1) {
      p0 += __shfl_down(p0, off);
      p1 += __shfl_down(p1, off);
    }
    if (t == 0) {
      out[b * 2 + 0] = p0 + fc2_b[0];
      out[b * 2 + 1] = p1 + fc2_b[1];
    }
  }
}

// ---------------------------------------------------------------------------
// Host launcher
// ws: [0,512K) Wq | [512K,768K) wif (f16 Wi, 128K used) | [768K,1792K) fc1T
//     | [1792K,18176K) U | [18176K,18304K) Cex | [18304K,18560K) FPg
//     | [18560K,+1K) Flg
// Cex/Flg need no init: 0xAA poison never matches a tag or the magic.
// ---------------------------------------------------------------------------
extern "C" void kernel_launch(void* const* d_in, const int* in_sizes, int n_in,
                              void* d_out, int out_size, void* d_ws, size_t ws_size,
                              hipStream_t stream) {
  const int* src = (const int*)d_in[0];
  const int* input_len = (const int*)d_in[1];
  const float* fix_src = (const float*)d_in[2];
  const float* emb = (const float*)d_in[3];
  const float* Wi = (const float*)d_in[4];
  const float* bi = (const float*)d_in[5];
  const float* Wh = (const float*)d_in[6];
  const float* bh = (const float*)d_in[7];
  const float* fc1_W = (const float*)d_in[8];
  const float* fc1_b = (const float*)d_in[9];
  const float* fc2_W = (const float*)d_in[10];
  const float* fc2_b = (const float*)d_in[11];
  float* out = (float*)d_out;

  char* ws = (char*)d_ws;
  uint4* Wq = (uint4*)(ws);                          // 512 KB
  f16* wif = (f16*)(ws + (512ull << 10));            // 128 KB used
  float* fc1T = (float*)(ws + (768ull << 10));       // 1 MB
  f16* U = (f16*)(ws + (1792ull << 10));             // 16 MB
  uint32_t* Cex = (uint32_t*)(ws + (18176ull << 10)); // 128 KB
  float* FPg = (float*)(ws + (18304ull << 10));      // 256 KB
  int* Flg = (int*)(ws + (18560ull << 10));          // 1 KB
  const size_t needed = (18561ull << 10);
  if (ws_size < needed) return;

  k_pack_wq<<<128, 256, 0, stream>>>(Wh, Wq);
  k_cvt_f16<<<(65536 + 255) / 256, 256, 0, stream>>>(Wi, wif, 65536);
  k_transpose8<<<(262144 + 255) / 256, 256, 0, stream>>>(fc1_W, fc1T, 1024, 262144);
  k_u_mfma<<<BB * SS / 64, 256, 0, stream>>>(src, emb, wif, bi, bh,
                                             input_len, U);
  k_recurrence<<<BB * 4, TT, 0, stream>>>(Wq, U, fix_src, input_len, fc1T,
                                          fc1_b, fc2_W, fc2_b, out, Cex, FPg,
                                          Flg);
}